// Round 5
// baseline (121.549 us; speedup 1.0000x reference)
//
#include <hip/hip_runtime.h>
#include <hip/hip_bf16.h>

#define NROWS 8192
#define DDIM  128
#define KTOT  256                  // concat K = [Qn | Kn]
#define TM    128                  // tile rows
#define NT    (NROWS / TM)         // 64 tiles per side
#define CHUNK 4                    // J-tiles per block
#define NBLK  544                  // sum over I of ceil((NT-I)/CHUNK)
#define ROWB  (KTOT * 2)           // 512 bytes per concat row

typedef unsigned short ushort_t;
typedef unsigned int   uint_t;
typedef __attribute__((ext_vector_type(8))) short          short8;
typedef __attribute__((ext_vector_type(8))) unsigned short ushort8;
typedef __attribute__((ext_vector_type(4))) float          floatx4;

// round-to-nearest-even fp32 -> bf16 bits
static __device__ inline ushort_t f2bf(float f) {
    union { float f; uint_t u; } a; a.f = f;
    uint_t u = a.u + 0x7fffu + ((a.u >> 16) & 1u);
    return (ushort_t)(u >> 16);
}

// K1: row-normalize q,k -> bf16 into single concat array G = [qn | kn] (8192 x 256).
__global__ __launch_bounds__(256) void norm_kernel(
    const float* __restrict__ q, const float* __restrict__ k,
    uint_t* __restrict__ G, double* acc)
{
    if (blockIdx.x == 0 && threadIdx.x == 0) *acc = 0.0;
    int wave = threadIdx.x >> 6;
    int lane = threadIdx.x & 63;
    int row  = blockIdx.x * 4 + wave;   // 2048 blocks x 4 waves = 8192 rows

    uint_t pq, pk;
    {
        const float2* r2 = (const float2*)(q + (size_t)row * DDIM);
        float2 v = r2[lane];
        float ss = v.x * v.x + v.y * v.y;
        #pragma unroll
        for (int o = 32; o > 0; o >>= 1) ss += __shfl_xor(ss, o, 64);
        float inv = rsqrtf(fmaxf(ss, 1e-16f));
        pq = (uint_t)f2bf(v.x * inv) | ((uint_t)f2bf(v.y * inv) << 16);
    }
    {
        const float2* r2 = (const float2*)(k + (size_t)row * DDIM);
        float2 v = r2[lane];
        float ss = v.x * v.x + v.y * v.y;
        #pragma unroll
        for (int o = 32; o > 0; o >>= 1) ss += __shfl_xor(ss, o, 64);
        float inv = rsqrtf(fmaxf(ss, 1e-16f));
        pk = (uint_t)f2bf(v.x * inv) | ((uint_t)f2bf(v.y * inv) << 16);
    }
    size_t rbase = (size_t)row * (KTOT / 2);   // uints per row = 128
    G[rbase + lane]      = pq;
    G[rbase + 64 + lane] = pk;
}

// K2: barrier-free gram-diff. Block = (I-tile, chunk of <=4 J-tiles).
// A-panel (wave's 64 rows x K=256) held in 128 VGPRs for the whole block;
// B-fragments streamed global->VGPR (no LDS, no __syncthreads in hot loop).
// C_IJ = A_I . B_J^T with B = [Qn | -Kn] (sign folded via XOR on kp>=4)
//      = qsim - ksim; accumulate sum C^2 (x2 for I!=J) into fp64 acc.
__global__ __launch_bounds__(256, 2) void gram_kernel(
    const ushort_t* __restrict__ G, double* acc)
{
    __shared__ float wsum[4];

    // decode blockIdx -> (I, j0): chunks of CHUNK over J = I..NT-1
    int c = blockIdx.x, I = 0;
    for (;;) {
        int nch = (NT - I + CHUNK - 1) / CHUNK;
        if (c < nch) break;
        c -= nch; ++I;
    }
    int j0 = I + c * CHUNK;
    int j1 = j0 + CHUNK; if (j1 > NT) j1 = NT;

    int tid  = threadIdx.x;
    int w    = tid >> 6;
    int l    = tid & 63;
    int m    = l & 15;
    int quad = l >> 4;
    int wr   = (w >> 1) * 64;     // wave quadrant rows
    int wc   = (w & 1) * 64;      // wave quadrant cols

    const char* gbase = (const char*)G;

    // ---- A-panel into registers: af[t][kp], 4 tiles x 8 k-phases x 4 VGPR = 128 VGPR
    short8 af[4][8];
    #pragma unroll
    for (int t = 0; t < 4; ++t) {
        const char* pa = gbase + (size_t)(I * TM + wr + t * 16 + m) * ROWB + quad * 16;
        #pragma unroll
        for (int kp = 0; kp < 8; ++kp)
            af[t][kp] = *(const short8*)(pa + kp * 64);
    }

    const ushort8 negmask = {0x8000,0x8000,0x8000,0x8000,0x8000,0x8000,0x8000,0x8000};
    float s = 0.f;

    for (int J = j0; J < j1; ++J) {
        floatx4 accC[4][4];
        #pragma unroll
        for (int t = 0; t < 4; ++t)
            #pragma unroll
            for (int u = 0; u < 4; ++u)
                accC[t][u] = (floatx4){0.f, 0.f, 0.f, 0.f};

        const char* pb[4];
        #pragma unroll
        for (int u = 0; u < 4; ++u)
            pb[u] = gbase + (size_t)(J * TM + wc + u * 16 + m) * ROWB + quad * 16;

        #pragma unroll
        for (int kp = 0; kp < 8; ++kp) {
            short8 bf[4];
            #pragma unroll
            for (int u = 0; u < 4; ++u) {
                short8 v = *(const short8*)(pb[u] + kp * 64);
                if (kp >= 4) v = (short8)((ushort8)v ^ negmask);   // -Kn half
                bf[u] = v;
            }
            #pragma unroll
            for (int t = 0; t < 4; ++t)
                #pragma unroll
                for (int u = 0; u < 4; ++u)
                    accC[t][u] = __builtin_amdgcn_mfma_f32_16x16x32_bf16(af[t][kp], bf[u], accC[t][u], 0, 0, 0);
        }

        float sp = 0.f;
        #pragma unroll
        for (int t = 0; t < 4; ++t)
            #pragma unroll
            for (int u = 0; u < 4; ++u)
                #pragma unroll
                for (int r = 0; r < 4; ++r) {
                    float d = accC[t][u][r];
                    sp += d * d;
                }
        s += (I == J) ? sp : 2.f * sp;
    }

    // block reduction -> fp64 atomic
    #pragma unroll
    for (int o = 32; o > 0; o >>= 1) s += __shfl_xor(s, o, 64);
    if (l == 0) wsum[w] = s;
    __syncthreads();
    if (tid == 0) {
        double t = (double)wsum[0] + (double)wsum[1] + (double)wsum[2] + (double)wsum[3];
        atomicAdd(acc, t);
    }
}

// K3: scale and emit scalar
__global__ void finalize_kernel(const double* acc, float* out) {
    out[0] = (float)(*acc * (1.0 / ((double)NROWS * (double)(NROWS - 1))));
}

extern "C" void kernel_launch(void* const* d_in, const int* in_sizes, int n_in,
                              void* d_out, int out_size, void* d_ws, size_t ws_size,
                              hipStream_t stream) {
    const float* q = (const float*)d_in[0];
    const float* k = (const float*)d_in[1];
    float* out = (float*)d_out;

    double* acc = (double*)d_ws;
    uint_t* G   = (uint_t*)((char*)d_ws + 256);   // 8192 x 256 bf16 = 4 MB

    norm_kernel<<<NROWS / 4, 256, 0, stream>>>(q, k, G, acc);
    gram_kernel<<<NBLK, 256, 0, stream>>>((const ushort_t*)G, acc);
    finalize_kernel<<<1, 1, 0, stream>>>(acc, out);
}

// Round 6
// 77.728 us; speedup vs baseline: 1.5638x; 1.5638x over previous
//
#include <hip/hip_runtime.h>
#include <hip/hip_bf16.h>

#define NROWS 8192
#define DDIM  128
#define KTOT  256                   // rows of Gt (a-dim): [Qn cols | Kn cols]
#define GT_ROWB (NROWS * 2)         // bytes per Gt row = 16384
#define NKCH  32                    // K-chunks over N
#define KCH   (NROWS / NKCH)        // 256 n-rows per chunk
#define LDSPAD 258                  // norm-kernel LDS row stride in shorts

typedef unsigned short ushort_t;
typedef unsigned int   uint_t;
typedef __attribute__((ext_vector_type(8))) short short8;
typedef __attribute__((ext_vector_type(4))) float floatx4;

#define LDS_PTR(p) ((__attribute__((address_space(3))) void*)(p))
#define GLB_PTR(p) ((const __attribute__((address_space(1))) void*)(p))

// round-to-nearest-even fp32 -> bf16 bits
static __device__ inline ushort_t f2bf(float f) {
    union { float f; uint_t u; } a; a.f = f;
    uint_t u = a.u + 0x7fffu + ((a.u >> 16) & 1u);
    return (ushort_t)(u >> 16);
}

// K1: row-normalize q,k -> bf16 and write TRANSPOSED Gt (256 x 8192):
// Gt[a][n] = Qn[n][a] for a<128, Kn[n][a-128] otherwise. LDS transpose,
// 64 n-rows per block. Also zeroes the fp64 accumulator.
__global__ __launch_bounds__(256) void norm_t_kernel(
    const float* __restrict__ q, const float* __restrict__ k,
    ushort_t* __restrict__ Gt, double* acc)
{
    __shared__ ushort_t lds[64 * LDSPAD];   // 33 KB, row stride 258 shorts
    if (blockIdx.x == 0 && threadIdx.x == 0) *acc = 0.0;
    int w = threadIdx.x >> 6;
    int l = threadIdx.x & 63;

    // phase 1: normalize 64 rows (16 per wave), deposit into LDS row-major
    #pragma unroll
    for (int i = 0; i < 16; ++i) {
        int rl  = w * 16 + i;                    // local n-row 0..63
        int row = blockIdx.x * 64 + rl;
        {
            float2 v = ((const float2*)(q + (size_t)row * DDIM))[l];
            float ss = v.x * v.x + v.y * v.y;
            #pragma unroll
            for (int o = 32; o > 0; o >>= 1) ss += __shfl_xor(ss, o, 64);
            float inv = rsqrtf(fmaxf(ss, 1e-16f));
            uint_t p = (uint_t)f2bf(v.x * inv) | ((uint_t)f2bf(v.y * inv) << 16);
            *(uint_t*)&lds[rl * LDSPAD + 2 * l] = p;          // cols 2l,2l+1
        }
        {
            float2 v = ((const float2*)(k + (size_t)row * DDIM))[l];
            float ss = v.x * v.x + v.y * v.y;
            #pragma unroll
            for (int o = 32; o > 0; o >>= 1) ss += __shfl_xor(ss, o, 64);
            float inv = rsqrtf(fmaxf(ss, 1e-16f));
            uint_t p = (uint_t)f2bf(v.x * inv) | ((uint_t)f2bf(v.y * inv) << 16);
            *(uint_t*)&lds[rl * LDSPAD + 128 + 2 * l] = p;    // cols 128+2l..
        }
    }
    __syncthreads();

    // phase 2: thread t owns Gt row a=t; gather 64 shorts from LDS column a,
    // store as 8 x 16B
    int a = threadIdx.x;
    char* gdst = (char*)Gt + (size_t)a * GT_ROWB + (size_t)blockIdx.x * 128;
    #pragma unroll
    for (int g = 0; g < 8; ++g) {
        union { ushort_t u16[8]; uint4 v; } tmp;
        #pragma unroll
        for (int e = 0; e < 8; ++e)
            tmp.u16[e] = lds[(g * 8 + e) * LDSPAD + a];
        *(uint4*)(gdst + g * 16) = tmp.v;
    }
}

// K2: partial Gram. Grid = 16 output tiles (64x64 of the 256x256 S=Gt.Gt^T)
// x 32 K-chunks (256 n each). 128 threads (2 waves). Panels staged via
// global_load_lds with XOR-chunk swizzle; MFMA 16x16x32 bf16.
// P[(tile*32+c)*4096 + r*64 + col] = partial S over this n-chunk.
__global__ __launch_bounds__(128) void gram_a_kernel(
    const ushort_t* __restrict__ Gt, float* __restrict__ P)
{
    __shared__ ushort_t sA[64 * KCH];   // 32 KB (row a-local x 256 n, swizzled)
    __shared__ ushort_t sB[64 * KCH];   // 32 KB

    int tile = blockIdx.x >> 5;         // 0..15
    int c    = blockIdx.x & 31;         // k-chunk
    int ti   = tile >> 2, tj = tile & 3;
    int tid  = threadIdx.x;

    const char* gA = (const char*)Gt + (size_t)(ti * 64) * GT_ROWB + c * (KCH * 2);
    const char* gB = (const char*)Gt + (size_t)(tj * 64) * GT_ROWB + c * (KCH * 2);

    // stage both 64x256 panels: 2048 16B-chunks each, 16 iters/thread
    #pragma unroll
    for (int it = 0; it < 16; ++it) {
        int chunk = it * 128 + tid;             // 0..2047
        int row = chunk >> 5, phys = chunk & 31;
        int logical = phys ^ (row & 7);
        __builtin_amdgcn_global_load_lds(GLB_PTR(gA + (size_t)row * GT_ROWB + logical * 16),
                                         LDS_PTR((char*)sA + chunk * 16), 16, 0, 0);
    }
    #pragma unroll
    for (int it = 0; it < 16; ++it) {
        int chunk = it * 128 + tid;
        int row = chunk >> 5, phys = chunk & 31;
        int logical = phys ^ (row & 7);
        __builtin_amdgcn_global_load_lds(GLB_PTR(gB + (size_t)row * GT_ROWB + logical * 16),
                                         LDS_PTR((char*)sB + chunk * 16), 16, 0, 0);
    }
    __syncthreads();

    int w    = tid >> 6;        // 0..1 : a-strip rows w*32..w*32+31
    int l    = tid & 63;
    int m    = l & 15;
    int quad = l >> 4;

    floatx4 accC[2][4];
    #pragma unroll
    for (int at = 0; at < 2; ++at)
        #pragma unroll
        for (int bt = 0; bt < 4; ++bt)
            accC[at][bt] = (floatx4){0.f, 0.f, 0.f, 0.f};

    #pragma unroll
    for (int kp = 0; kp < 8; ++kp) {
        short8 af[2], bf[4];
        #pragma unroll
        for (int at = 0; at < 2; ++at) {
            int ra   = w * 32 + at * 16 + m;
            int phys = (kp * 4 + quad) ^ (ra & 7);
            af[at] = *(const short8*)&sA[ra * KCH + phys * 8];
        }
        #pragma unroll
        for (int bt = 0; bt < 4; ++bt) {
            int rb   = bt * 16 + m;
            int phys = (kp * 4 + quad) ^ (rb & 7);
            bf[bt] = *(const short8*)&sB[rb * KCH + phys * 8];
        }
        #pragma unroll
        for (int at = 0; at < 2; ++at)
            #pragma unroll
            for (int bt = 0; bt < 4; ++bt)
                accC[at][bt] = __builtin_amdgcn_mfma_f32_16x16x32_bf16(af[at], bf[bt], accC[at][bt], 0, 0, 0);
    }

    // write 64x64 fp32 partial tile (C layout: col=m, row=quad*4+reg)
    float* pt = P + ((size_t)tile * NKCH + c) * 4096;
    #pragma unroll
    for (int at = 0; at < 2; ++at)
        #pragma unroll
        for (int bt = 0; bt < 4; ++bt)
            #pragma unroll
            for (int r = 0; r < 4; ++r) {
                int row = w * 32 + at * 16 + quad * 4 + r;
                int col = bt * 16 + m;
                pt[row * 64 + col] = accC[at][bt][r];
            }
}

// K3: reduce partials over 32 chunks, apply per-tile +/-1 weight, square,
// accumulate into fp64 scalar.
__global__ __launch_bounds__(256) void gram_b_kernel(
    const float* __restrict__ P, double* acc)
{
    __shared__ float wsum[4];
    int e    = blockIdx.x * 256 + threadIdx.x;   // 0..65535
    int tile = e >> 12;
    int idx  = e & 4095;

    float s = 0.f;
    #pragma unroll
    for (int c = 0; c < NKCH; ++c)
        s += P[((size_t)tile * NKCH + c) * 4096 + idx];

    int ti = tile >> 2, tj = tile & 3;
    float wgt = ((ti < 2) == (tj < 2)) ? 1.f : -1.f;
    float v = wgt * s * s;

    int w = threadIdx.x >> 6, l = threadIdx.x & 63;
    #pragma unroll
    for (int o = 32; o > 0; o >>= 1) v += __shfl_xor(v, o, 64);
    if (l == 0) wsum[w] = v;
    __syncthreads();
    if (threadIdx.x == 0) {
        double t = (double)wsum[0] + (double)wsum[1] + (double)wsum[2] + (double)wsum[3];
        atomicAdd(acc, t);
    }
}

// K4: scale and emit scalar
__global__ void finalize_kernel(const double* acc, float* out) {
    out[0] = (float)(*acc * (1.0 / ((double)NROWS * (double)(NROWS - 1))));
}

extern "C" void kernel_launch(void* const* d_in, const int* in_sizes, int n_in,
                              void* d_out, int out_size, void* d_ws, size_t ws_size,
                              hipStream_t stream) {
    const float* q = (const float*)d_in[0];
    const float* k = (const float*)d_in[1];
    float* out = (float*)d_out;

    double*   acc = (double*)d_ws;
    ushort_t* Gt  = (ushort_t*)((char*)d_ws + 256);                    // 256 x 8192 bf16 = 4 MB
    float*    P   = (float*)((char*)d_ws + 256 + (size_t)KTOT * GT_ROWB); // 512 x 16 KB = 8.4 MB

    norm_t_kernel<<<NROWS / 64, 256, 0, stream>>>(q, k, Gt, acc);
    gram_a_kernel<<<16 * NKCH, 128, 0, stream>>>(Gt, P);
    gram_b_kernel<<<256, 256, 0, stream>>>(P, acc);
    finalize_kernel<<<1, 1, 0, stream>>>(acc, out);
}

// Round 7
// 76.346 us; speedup vs baseline: 1.5921x; 1.0181x over previous
//
#include <hip/hip_runtime.h>
#include <hip/hip_bf16.h>

#define NROWS 8192
#define DDIM  128
#define KTOT  256                   // rows of Gt (a-dim): [Qn cols | Kn cols]
#define GT_ROWB (NROWS * 2)         // bytes per Gt row = 16384
#define NKCH  64                    // K-chunks over N
#define CHN   (NROWS / NKCH)        // 128 n-rows per chunk
#define NPAIR 10                    // triangular (ti<=tj) over 4 a-groups
#define GB_BLOCKS 160               // gram_b grid (10*4096/256)
#define LDSPAD 260                  // norm LDS row stride in shorts (8B-aligned rows)

typedef unsigned short ushort_t;
typedef unsigned int   uint_t;
typedef __attribute__((ext_vector_type(8))) short short8;
typedef __attribute__((ext_vector_type(4))) float floatx4;

#define LDS_PTR(p) ((__attribute__((address_space(3))) void*)(p))
#define GLB_PTR(p) ((const __attribute__((address_space(1))) void*)(p))

// round-to-nearest-even fp32 -> bf16 bits
static __device__ inline ushort_t f2bf(float f) {
    union { float f; uint_t u; } a; a.f = f;
    uint_t u = a.u + 0x7fffu + ((a.u >> 16) & 1u);
    return (ushort_t)(u >> 16);
}

// decode triangular pair p -> (ti,tj), ti<=tj over 4 groups
static __device__ inline void pair_decode(int p, int* ti, int* tj) {
    int i = 0, len = 4;
    while (p >= len) { p -= len; len--; i++; }
    *ti = i; *tj = i + p;
}

// K1: row-normalize q,k -> bf16, write TRANSPOSED Gt (256 x 8192).
// Two rows per wave-pass (32-lane halves, float4/lane), LDS transpose.
// Also zeroes the fp64 accumulator + done-counter.
__global__ __launch_bounds__(256) void norm_t_kernel(
    const float* __restrict__ q, const float* __restrict__ k,
    ushort_t* __restrict__ Gt, double* acc, uint_t* counter)
{
    __shared__ ushort_t lds[64 * LDSPAD];   // 33.3 KB
    if (blockIdx.x == 0 && threadIdx.x == 0) { *acc = 0.0; *counter = 0u; }
    int w  = threadIdx.x >> 6;
    int l  = threadIdx.x & 63;
    int h  = l >> 5;          // half-wave: row parity
    int li = l & 31;          // lane within half: 4 floats each

    #pragma unroll
    for (int i = 0; i < 8; ++i) {
        int rl  = w * 16 + 2 * i + h;            // local n-row 0..63
        int row = blockIdx.x * 64 + rl;
        {
            float4 v = ((const float4*)(q + (size_t)row * DDIM))[li];
            float ss = v.x * v.x + v.y * v.y + v.z * v.z + v.w * v.w;
            #pragma unroll
            for (int o = 16; o > 0; o >>= 1) ss += __shfl_xor(ss, o, 64);
            float inv = rsqrtf(fmaxf(ss, 1e-16f));
            uint2 p2;
            p2.x = (uint_t)f2bf(v.x * inv) | ((uint_t)f2bf(v.y * inv) << 16);
            p2.y = (uint_t)f2bf(v.z * inv) | ((uint_t)f2bf(v.w * inv) << 16);
            *(uint2*)&lds[rl * LDSPAD + 4 * li] = p2;           // cols 4li..4li+3
        }
        {
            float4 v = ((const float4*)(k + (size_t)row * DDIM))[li];
            float ss = v.x * v.x + v.y * v.y + v.z * v.z + v.w * v.w;
            #pragma unroll
            for (int o = 16; o > 0; o >>= 1) ss += __shfl_xor(ss, o, 64);
            float inv = rsqrtf(fmaxf(ss, 1e-16f));
            uint2 p2;
            p2.x = (uint_t)f2bf(v.x * inv) | ((uint_t)f2bf(v.y * inv) << 16);
            p2.y = (uint_t)f2bf(v.z * inv) | ((uint_t)f2bf(v.w * inv) << 16);
            *(uint2*)&lds[rl * LDSPAD + 128 + 4 * li] = p2;     // cols 128+4li..
        }
    }
    __syncthreads();

    // phase 2: thread owns Gt row a=tid; gather 64 shorts from LDS column a
    int a = threadIdx.x;
    char* gdst = (char*)Gt + (size_t)a * GT_ROWB + (size_t)blockIdx.x * 128;
    #pragma unroll
    for (int g = 0; g < 8; ++g) {
        union { ushort_t u16[8]; uint4 v; } tmp;
        #pragma unroll
        for (int e = 0; e < 8; ++e)
            tmp.u16[e] = lds[(g * 8 + e) * LDSPAD + a];
        *(uint4*)(gdst + g * 16) = tmp.v;
    }
}

// K2: partial Gram. Grid = 10 symmetric tiles x 64 K-chunks (128 n each) = 640
// blocks, 128 threads, 32 KB LDS -> ~5 blocks/CU (10 waves/CU). Panels staged
// via global_load_lds with XOR-chunk swizzle; MFMA 16x16x32 bf16.
__global__ __launch_bounds__(128, 2) void gram_a_kernel(
    const ushort_t* __restrict__ Gt, float* __restrict__ P)
{
    __shared__ ushort_t sA[64 * CHN];   // 16 KB
    __shared__ ushort_t sB[64 * CHN];   // 16 KB

    int pair = blockIdx.x >> 6;         // 0..9
    int c    = blockIdx.x & 63;         // k-chunk
    int ti, tj;
    pair_decode(pair, &ti, &tj);
    int tid = threadIdx.x;

    const char* gA = (const char*)Gt + (size_t)(ti * 64) * GT_ROWB + c * (CHN * 2);
    const char* gB = (const char*)Gt + (size_t)(tj * 64) * GT_ROWB + c * (CHN * 2);

    // stage both 64x128 panels: 1024 16B-chunks each, 8 iters/thread
    #pragma unroll
    for (int it = 0; it < 8; ++it) {
        int ch = it * 128 + tid;               // 0..1023
        int row = ch >> 4, phys = ch & 15;
        int logical = phys ^ (row & 7);
        __builtin_amdgcn_global_load_lds(GLB_PTR(gA + (size_t)row * GT_ROWB + logical * 16),
                                         LDS_PTR((char*)sA + ch * 16), 16, 0, 0);
    }
    #pragma unroll
    for (int it = 0; it < 8; ++it) {
        int ch = it * 128 + tid;
        int row = ch >> 4, phys = ch & 15;
        int logical = phys ^ (row & 7);
        __builtin_amdgcn_global_load_lds(GLB_PTR(gB + (size_t)row * GT_ROWB + logical * 16),
                                         LDS_PTR((char*)sB + ch * 16), 16, 0, 0);
    }
    __syncthreads();

    int w    = tid >> 6;        // a-strip: rows w*32..w*32+31
    int l    = tid & 63;
    int m    = l & 15;
    int quad = l >> 4;

    floatx4 accC[2][4];
    #pragma unroll
    for (int at = 0; at < 2; ++at)
        #pragma unroll
        for (int bt = 0; bt < 4; ++bt)
            accC[at][bt] = (floatx4){0.f, 0.f, 0.f, 0.f};

    #pragma unroll
    for (int kp = 0; kp < 4; ++kp) {
        short8 af[2], bf[4];
        #pragma unroll
        for (int at = 0; at < 2; ++at) {
            int ra   = w * 32 + at * 16 + m;
            int phys = (kp * 4 + quad) ^ (ra & 7);
            af[at] = *(const short8*)&sA[ra * CHN + phys * 8];
        }
        #pragma unroll
        for (int bt = 0; bt < 4; ++bt) {
            int rb   = bt * 16 + m;
            int phys = (kp * 4 + quad) ^ (rb & 7);
            bf[bt] = *(const short8*)&sB[rb * CHN + phys * 8];
        }
        #pragma unroll
        for (int at = 0; at < 2; ++at)
            #pragma unroll
            for (int bt = 0; bt < 4; ++bt)
                accC[at][bt] = __builtin_amdgcn_mfma_f32_16x16x32_bf16(af[at], bf[bt], accC[at][bt], 0, 0, 0);
    }

    // write 64x64 fp32 partial (C layout: col=m, row=quad*4+reg)
    float* pt = P + ((size_t)pair * NKCH + c) * 4096;
    #pragma unroll
    for (int at = 0; at < 2; ++at)
        #pragma unroll
        for (int bt = 0; bt < 4; ++bt)
            #pragma unroll
            for (int r = 0; r < 4; ++r) {
                int row = w * 32 + at * 16 + quad * 4 + r;
                int col = bt * 16 + m;
                pt[row * 64 + col] = accC[at][bt][r];
            }
}

// K3: reduce partials over 64 chunks, apply per-tile weight (sign x symmetry),
// square, accumulate into fp64 scalar; LAST block finalizes into out.
__global__ __launch_bounds__(256) void gram_b_kernel(
    const float* __restrict__ P, double* acc, uint_t* counter, float* out)
{
    __shared__ float wsum[4];
    int e    = blockIdx.x * 256 + threadIdx.x;   // 0..40959
    int pair = e >> 12;
    int idx  = e & 4095;

    float s = 0.f;
    #pragma unroll
    for (int c = 0; c < NKCH; ++c)
        s += P[((size_t)pair * NKCH + c) * 4096 + idx];

    int ti, tj;
    pair_decode(pair, &ti, &tj);
    float wgt = ((ti < 2) == (tj < 2)) ? 1.f : -1.f;
    if (ti != tj) wgt *= 2.f;                    // symmetric tile counted twice
    float v = wgt * s * s;

    int w = threadIdx.x >> 6, l = threadIdx.x & 63;
    #pragma unroll
    for (int o = 32; o > 0; o >>= 1) v += __shfl_xor(v, o, 64);
    if (l == 0) wsum[w] = v;
    __syncthreads();
    if (threadIdx.x == 0) {
        double t = (double)wsum[0] + (double)wsum[1] + (double)wsum[2] + (double)wsum[3];
        atomicAdd(acc, t);
        __threadfence();
        uint_t old = atomicAdd(counter, 1u);
        if (old == GB_BLOCKS - 1) {
            double total = atomicAdd(acc, 0.0);  // coherent read of final sum
            out[0] = (float)(total * (1.0 / ((double)NROWS * (double)(NROWS - 1))));
        }
    }
}

extern "C" void kernel_launch(void* const* d_in, const int* in_sizes, int n_in,
                              void* d_out, int out_size, void* d_ws, size_t ws_size,
                              hipStream_t stream) {
    const float* q = (const float*)d_in[0];
    const float* k = (const float*)d_in[1];
    float* out = (float*)d_out;

    double*   acc = (double*)d_ws;
    uint_t*   cnt = (uint_t*)((char*)d_ws + 64);
    ushort_t* Gt  = (ushort_t*)((char*)d_ws + 256);                        // 4 MB
    float*    P   = (float*)((char*)d_ws + 256 + (size_t)KTOT * GT_ROWB);  // 10 MB

    norm_t_kernel<<<NROWS / 64, 256, 0, stream>>>(q, k, Gt, acc, cnt);
    gram_a_kernel<<<NPAIR * NKCH, 128, 0, stream>>>(Gt, P);
    gram_b_kernel<<<GB_BLOCKS, 256, 0, stream>>>(P, acc, cnt, out);
}